// Round 5
// baseline (799.576 us; speedup 1.0000x reference)
//
#include <hip/hip_runtime.h>
#include <hip/hip_bf16.h>

// Problem constants (B=16, N=S=2048, D=256, fp32 in/out).
#define BB 16
#define NN 2048
#define SS 2048
#define DD 256
#define EE (BB * NN * DD)  // 8388608 elements per tensor

typedef __bf16 bf16x8 __attribute__((ext_vector_type(8)));
typedef __bf16 bf16x4 __attribute__((ext_vector_type(4)));
typedef float floatx4 __attribute__((ext_vector_type(4)));

__device__ __forceinline__ void async16(const __bf16* g, __bf16* l) {
    __builtin_amdgcn_global_load_lds((__attribute__((address_space(1))) void*)g,
                                     (__attribute__((address_space(3))) void*)l, 16, 0, 0);
}

__device__ __forceinline__ void nt_store4(float* p, float x, float y, float z, float w) {
    floatx4 v = {x, y, z, w};
    __builtin_nontemporal_store(v, (floatx4*)p);
}

// ---------------------------------------------------------------------------
// Kernel 0: split Q and K (fp32) into bf16 hi/lo pairs (4 separate matrices —
// the round-3 layout that passed). Stash lives in the A-output region, which
// the fused sparsemax kernel overwrites later in the same launch.
// stash layout (bf16): Qhi[EE] | Qlo[EE] | Khi[EE] | Klo[EE]  = 67 MB
// ---------------------------------------------------------------------------
__global__ __launch_bounds__(256) void k_convert(const float* __restrict__ Q,
                                                 const float* __restrict__ K,
                                                 __bf16* __restrict__ stash) {
    size_t idx = ((size_t)blockIdx.x * 256 + threadIdx.x) * 4;  // over 2*EE elems
    const float* src;
    __bf16 *dh, *dl;
    size_t off;
    if (idx < (size_t)EE) {
        src = Q; dh = stash; dl = stash + (size_t)EE; off = idx;
    } else {
        src = K; dh = stash + 2 * (size_t)EE; dl = stash + 3 * (size_t)EE; off = idx - (size_t)EE;
    }
    float4 v = *(const float4*)(src + off);
    bf16x4 h, l;
    h.x = (__bf16)v.x; h.y = (__bf16)v.y; h.z = (__bf16)v.z; h.w = (__bf16)v.w;
    l.x = (__bf16)(v.x - (float)h.x);
    l.y = (__bf16)(v.y - (float)h.y);
    l.z = (__bf16)(v.z - (float)h.z);
    l.w = (__bf16)(v.w - (float)h.w);
    *(bf16x4*)(dh + off) = h;
    *(bf16x4*)(dl + off) = l;
}

// ---------------------------------------------------------------------------
// Kernel 1: scores = Q @ K^T via 3-term split-bf16 MFMA (qh*kh + qh*kl + ql*kh;
// the dropped ql*kl term is ~2^-18 relative — verified in rounds 2-3).
// 128x128 tile / block, 4 waves each 64x64 (4x4 tiles of 16x16x32).
//
// XCD-aware supertile swizzle: wg i dispatches to XCD (i&7); j = i>>3 walks
// 4 jobs per XCD, each job = (1 batch, 8 n-strips x 16 s-strips) -> per-job
// working set = 1 MB Q-strip + 2 MB K-batch = 3 MB < 4 MB XCD L2, so stash
// staging hits L2 instead of re-fetching ~1 GB from HBM.
// ---------------------------------------------------------------------------
__global__ __launch_bounds__(256) void k_scores_mfma(const __bf16* __restrict__ stash,
                                                     float* __restrict__ out) {
    __shared__ __bf16 Qh[128 * 32];
    __shared__ __bf16 Ql[128 * 32];
    __shared__ __bf16 Kh[128 * 32];
    __shared__ __bf16 Kl[128 * 32];

    const __bf16* Qhi = stash;
    const __bf16* Qlo = stash + (size_t)EE;
    const __bf16* Khi = stash + 2 * (size_t)EE;
    const __bf16* Klo = stash + 3 * (size_t)EE;

    // supertile decode (assumes round-robin wg->XCD: xcd = id % 8)
    const int id    = blockIdx.x;
    const int xcd   = id & 7;
    const int j     = id >> 3;            // 0..511 sequential within an XCD
    const int jobg  = xcd * 4 + (j >> 7); // 0..31 = (batch, n-half)
    const int b     = jobg >> 1;
    const int nh    = jobg & 1;
    const int local = j & 127;
    const int n0    = ((nh << 3) + (local >> 4)) << 7;  // 8 n-strips per job
    const int s0    = (local & 15) << 7;                // 16 s-strips per job

    const int t    = threadIdx.x;
    const int wave = t >> 6;
    const int lane = t & 63;

    // staging: row within 64-row pass, 16B d-chunk (LDS dst = base + lane*16B)
    const int srow = (wave << 4) + (lane >> 2);   // 0..63
    const int sd   = (lane & 3) << 3;             // 0,8,16,24 elems
    const int lds0 = srow * 32 + sd;
    const size_t qg = (size_t)b * NN * DD + (size_t)(n0 + srow) * DD + sd;
    const size_t kg = (size_t)b * SS * DD + (size_t)(s0 + srow) * DD + sd;

    // fragment read offsets: A[m = lane&15][k-quad = lane>>4], 8 elems/quad
    const int wy = wave >> 1, wx = wave & 1;
    const int frag = (lane & 15) * 32 + (lane >> 4) * 8;

    floatx4 acc[4][4] = {};

    for (int d0 = 0; d0 < DD; d0 += 32) {
        __syncthreads();
        async16(Qhi + qg + d0,            &Qh[lds0]);
        async16(Qhi + qg + d0 + 64 * DD,  &Qh[lds0 + 2048]);
        async16(Qlo + qg + d0,            &Ql[lds0]);
        async16(Qlo + qg + d0 + 64 * DD,  &Ql[lds0 + 2048]);
        async16(Khi + kg + d0,            &Kh[lds0]);
        async16(Khi + kg + d0 + 64 * DD,  &Kh[lds0 + 2048]);
        async16(Klo + kg + d0,            &Kl[lds0]);
        async16(Klo + kg + d0 + 64 * DD,  &Kl[lds0 + 2048]);
        __syncthreads();

        bf16x8 qh[4], ql[4], kh[4], kl[4];
#pragma unroll
        for (int i = 0; i < 4; ++i) {
            qh[i] = *(const bf16x8*)&Qh[(wy * 64 + i * 16) * 32 + frag];
            ql[i] = *(const bf16x8*)&Ql[(wy * 64 + i * 16) * 32 + frag];
            kh[i] = *(const bf16x8*)&Kh[(wx * 64 + i * 16) * 32 + frag];
            kl[i] = *(const bf16x8*)&Kl[(wx * 64 + i * 16) * 32 + frag];
        }
#pragma unroll
        for (int i = 0; i < 4; ++i)
#pragma unroll
            for (int j2 = 0; j2 < 4; ++j2) {
                acc[i][j2] = __builtin_amdgcn_mfma_f32_16x16x32_bf16(qh[i], kh[j2], acc[i][j2], 0, 0, 0);
                acc[i][j2] = __builtin_amdgcn_mfma_f32_16x16x32_bf16(qh[i], kl[j2], acc[i][j2], 0, 0, 0);
                acc[i][j2] = __builtin_amdgcn_mfma_f32_16x16x32_bf16(ql[i], kh[j2], acc[i][j2], 0, 0, 0);
            }
    }

    // C/D layout: col = lane&15, row = (lane>>4)*4 + reg. Nontemporal: scores
    // are re-read only by the (much later) sparsemax kernel — keep L2 for stash.
    float* ob = out + (size_t)b * NN * SS;
    const int r0 = n0 + wy * 64 + (lane >> 4) * 4;
    const int c0 = s0 + wx * 64 + (lane & 15);
#pragma unroll
    for (int i = 0; i < 4; ++i)
#pragma unroll
        for (int j2 = 0; j2 < 4; ++j2)
#pragma unroll
            for (int r = 0; r < 4; ++r)
                __builtin_nontemporal_store(acc[i][j2][r],
                    ob + (size_t)(r0 + i * 16 + r) * SS + c0 + j2 * 16);
}

// ---------------------------------------------------------------------------
// Kernel 2 (fused): row-wise sparsemax + sparse PV (unchanged from round 3).
// One wave per row. tau: 10 bisection steps to bracket, then 4 Michelot
// refines (exact fixpoint). Gates nt-stored to gates and A regions; PV
// gathered from ballot'd nonzeros (support k ~ 1-2 per row).
// ---------------------------------------------------------------------------
__global__ __launch_bounds__(256) void k_sparsemax_pv(float* __restrict__ G,
                                                      float* __restrict__ A,
                                                      const float* __restrict__ Val,
                                                      float* __restrict__ Vout) {
    const int t = threadIdx.x;
    const int lane = t & 63;
    const size_t row = (size_t)blockIdx.x * 4 + (t >> 6);  // over B*N
    const int b = (int)(row >> 11);                        // NN = 2048
    float* z = G + row * SS;
    float* arow = A + row * SS;
    const float* vb = Val + (size_t)b * SS * DD;

    float v[32];
#pragma unroll
    for (int c = 0; c < 8; ++c) {
        float4 zz = *(const float4*)(z + c * 256 + (lane << 2));
        v[c * 4 + 0] = zz.x; v[c * 4 + 1] = zz.y; v[c * 4 + 2] = zz.z; v[c * 4 + 3] = zz.w;
    }

    // wave max
    float m = v[0];
#pragma unroll
    for (int j = 1; j < 32; ++j) m = fmaxf(m, v[j]);
#pragma unroll
    for (int off = 32; off > 0; off >>= 1) m = fmaxf(m, __shfl_xor(m, off, 64));

    // bisection to bracket the support: g(lo) >= 1 >= g(hi)
    float lo = m - 1.0f, hi = m;
    for (int it = 0; it < 10; ++it) {
        float mid = 0.5f * (lo + hi);
        float p = 0.f;
#pragma unroll
        for (int j = 0; j < 32; ++j) p += fmaxf(v[j] - mid, 0.f);
#pragma unroll
        for (int off = 32; off > 0; off >>= 1) p += __shfl_xor(p, off, 64);
        if (p >= 1.0f) lo = mid; else hi = mid;
    }

    // Michelot refines: tau increases monotonically to the exact threshold
    float tau = lo;
#pragma unroll
    for (int it = 0; it < 4; ++it) {
        float cnt = 0.f, s = 0.f;
#pragma unroll
        for (int j = 0; j < 32; ++j) {
            if (v[j] > tau) { cnt += 1.0f; s += v[j]; }
        }
#pragma unroll
        for (int off = 32; off > 0; off >>= 1) {
            cnt += __shfl_xor(cnt, off, 64);
            s   += __shfl_xor(s, off, 64);
        }
        tau = (s - 1.0f) / cnt;
    }

    // gates (kept in registers for PV), dual nontemporal store
    float g[32];
#pragma unroll
    for (int c = 0; c < 8; ++c) {
#pragma unroll
        for (int q = 0; q < 4; ++q) g[c * 4 + q] = fmaxf(v[c * 4 + q] - tau, 0.f);
        nt_store4(z + c * 256 + (lane << 2),    g[c * 4], g[c * 4 + 1], g[c * 4 + 2], g[c * 4 + 3]);
        nt_store4(arow + c * 256 + (lane << 2), g[c * 4], g[c * 4 + 1], g[c * 4 + 2], g[c * 4 + 3]);
    }

    // sparse PV from registers
    float4 acc = make_float4(0.f, 0.f, 0.f, 0.f);
#pragma unroll
    for (int c = 0; c < 8; ++c) {
#pragma unroll
        for (int q = 0; q < 4; ++q) {
            float a = g[c * 4 + q];
            unsigned long long mask = __ballot(a != 0.0f);
            while (mask) {
                int src = __builtin_ctzll(mask);
                mask &= mask - 1;
                float aa = __shfl(a, src, 64);
                int s = c * 256 + src * 4 + q;
                float4 vv = *(const float4*)(vb + (size_t)s * DD + lane * 4);
                acc.x += aa * vv.x;
                acc.y += aa * vv.y;
                acc.z += aa * vv.z;
                acc.w += aa * vv.w;
            }
        }
    }

    nt_store4(Vout + row * DD + lane * 4, acc.x, acc.y, acc.z, acc.w);
}

extern "C" void kernel_launch(void* const* d_in, const int* in_sizes, int n_in,
                              void* d_out, int out_size, void* d_ws, size_t ws_size,
                              hipStream_t stream) {
    const float* Q = (const float*)d_in[0];
    const float* K = (const float*)d_in[1];
    const float* V = (const float*)d_in[2];

    float* out  = (float*)d_out;
    float* Vout = out;                                   // [B,N,D]
    float* Aout = out + (size_t)BB * NN * DD;            // [B,N,S]
    float* Gout = Aout + (size_t)BB * NN * SS;           // [B,N,S]

    // 0) split Q,K into bf16 hi/lo stash (lives in Aout region until sparsemax)
    __bf16* stash = (__bf16*)Aout;
    hipLaunchKernelGGL(k_convert, dim3((2 * EE / 4) / 256), dim3(256), 0, stream, Q, K, stash);

    // 1) scores -> gates region (3-term split-bf16 MFMA, XCD-swizzled grid)
    hipLaunchKernelGGL(k_scores_mfma, dim3(4096), dim3(256), 0, stream, stash, Gout);

    // 2) fused sparsemax + PV: gates in-place, duplicate into A, V out
    hipLaunchKernelGGL(k_sparsemax_pv, dim3((BB * NN) / 4), dim3(256), 0, stream,
                       Gout, Aout, V, Vout);
}

// Round 6
// 762.765 us; speedup vs baseline: 1.0483x; 1.0483x over previous
//
#include <hip/hip_runtime.h>
#include <hip/hip_bf16.h>

// Problem constants (B=16, N=S=2048, D=256, fp32 in/out).
#define BB 16
#define NN 2048
#define SS 2048
#define DD 256
#define EE (BB * NN * DD)  // 8388608 elements per tensor

typedef __bf16 bf16x8 __attribute__((ext_vector_type(8)));
typedef __bf16 bf16x4 __attribute__((ext_vector_type(4)));
typedef float floatx4 __attribute__((ext_vector_type(4)));

__device__ __forceinline__ void async16(const __bf16* g, __bf16* l) {
    __builtin_amdgcn_global_load_lds((__attribute__((address_space(1))) void*)g,
                                     (__attribute__((address_space(3))) void*)l, 16, 0, 0);
}

__device__ __forceinline__ void nt_store4(float* p, float x, float y, float z, float w) {
    floatx4 v = {x, y, z, w};
    __builtin_nontemporal_store(v, (floatx4*)p);
}

// ---------------------------------------------------------------------------
// Kernel 0: split Q and K (fp32) into bf16 hi/lo pairs.
// stash layout (bf16): Qhi[EE] | Qlo[EE] | Khi[EE] | Klo[EE]  = 67 MB
// Stash lives in the A-output region (overwritten later by sparsemax).
// ---------------------------------------------------------------------------
__global__ __launch_bounds__(256) void k_convert(const float* __restrict__ Q,
                                                 const float* __restrict__ K,
                                                 __bf16* __restrict__ stash) {
    size_t idx = ((size_t)blockIdx.x * 256 + threadIdx.x) * 4;  // over 2*EE elems
    const float* src;
    __bf16 *dh, *dl;
    size_t off;
    if (idx < (size_t)EE) {
        src = Q; dh = stash; dl = stash + (size_t)EE; off = idx;
    } else {
        src = K; dh = stash + 2 * (size_t)EE; dl = stash + 3 * (size_t)EE; off = idx - (size_t)EE;
    }
    float4 v = *(const float4*)(src + off);
    bf16x4 h, l;
    h.x = (__bf16)v.x; h.y = (__bf16)v.y; h.z = (__bf16)v.z; h.w = (__bf16)v.w;
    l.x = (__bf16)(v.x - (float)h.x);
    l.y = (__bf16)(v.y - (float)h.y);
    l.z = (__bf16)(v.z - (float)h.z);
    l.w = (__bf16)(v.w - (float)h.w);
    *(bf16x4*)(dh + off) = h;
    *(bf16x4*)(dl + off) = l;
}

// ---------------------------------------------------------------------------
// Kernel 1: scores = Q @ K^T via 3-term split-bf16 MFMA (qh*kh + qh*kl + ql*kh).
// 128x128 tile / block, 4 waves each 64x64 (4x4 tiles of 16x16x32).
// R3-identical (plain grid, normal cached C-writes — the write leaves ~95% of
// scores resident in the 256 MB L3 for the next kernel; do NOT nt this store).
// ---------------------------------------------------------------------------
__global__ __launch_bounds__(256) void k_scores_mfma(const __bf16* __restrict__ stash,
                                                     float* __restrict__ out) {
    __shared__ __bf16 Qh[128 * 32];
    __shared__ __bf16 Ql[128 * 32];
    __shared__ __bf16 Kh[128 * 32];
    __shared__ __bf16 Kl[128 * 32];

    const __bf16* Qhi = stash;
    const __bf16* Qlo = stash + (size_t)EE;
    const __bf16* Khi = stash + 2 * (size_t)EE;
    const __bf16* Klo = stash + 3 * (size_t)EE;

    const int b  = blockIdx.z;
    const int n0 = blockIdx.y * 128;
    const int s0 = blockIdx.x * 128;

    const int t    = threadIdx.x;
    const int wave = t >> 6;
    const int lane = t & 63;

    // staging: row within 64-row pass, 16B d-chunk
    const int srow = (wave << 4) + (lane >> 2);   // 0..63
    const int sd   = (lane & 3) << 3;             // 0,8,16,24 elems
    const int lds0 = srow * 32 + sd;
    const size_t qg = (size_t)b * NN * DD + (size_t)(n0 + srow) * DD + sd;
    const size_t kg = (size_t)b * SS * DD + (size_t)(s0 + srow) * DD + sd;

    // fragment read offsets
    const int wy = wave >> 1, wx = wave & 1;
    const int frag = (lane & 15) * 32 + (lane >> 4) * 8;

    floatx4 acc[4][4] = {};

    for (int d0 = 0; d0 < DD; d0 += 32) {
        __syncthreads();
        async16(Qhi + qg + d0,            &Qh[lds0]);
        async16(Qhi + qg + d0 + 64 * DD,  &Qh[lds0 + 2048]);
        async16(Qlo + qg + d0,            &Ql[lds0]);
        async16(Qlo + qg + d0 + 64 * DD,  &Ql[lds0 + 2048]);
        async16(Khi + kg + d0,            &Kh[lds0]);
        async16(Khi + kg + d0 + 64 * DD,  &Kh[lds0 + 2048]);
        async16(Klo + kg + d0,            &Kl[lds0]);
        async16(Klo + kg + d0 + 64 * DD,  &Kl[lds0 + 2048]);
        __syncthreads();

        bf16x8 qh[4], ql[4], kh[4], kl[4];
#pragma unroll
        for (int i = 0; i < 4; ++i) {
            qh[i] = *(const bf16x8*)&Qh[(wy * 64 + i * 16) * 32 + frag];
            ql[i] = *(const bf16x8*)&Ql[(wy * 64 + i * 16) * 32 + frag];
            kh[i] = *(const bf16x8*)&Kh[(wx * 64 + i * 16) * 32 + frag];
            kl[i] = *(const bf16x8*)&Kl[(wx * 64 + i * 16) * 32 + frag];
        }
#pragma unroll
        for (int i = 0; i < 4; ++i)
#pragma unroll
            for (int j = 0; j < 4; ++j) {
                acc[i][j] = __builtin_amdgcn_mfma_f32_16x16x32_bf16(qh[i], kh[j], acc[i][j], 0, 0, 0);
                acc[i][j] = __builtin_amdgcn_mfma_f32_16x16x32_bf16(qh[i], kl[j], acc[i][j], 0, 0, 0);
                acc[i][j] = __builtin_amdgcn_mfma_f32_16x16x32_bf16(ql[i], kh[j], acc[i][j], 0, 0, 0);
            }
    }

    // C/D layout: col = lane&15, row = (lane>>4)*4 + reg
    float* ob = out + (size_t)b * NN * SS;
    const int r0 = n0 + wy * 64 + (lane >> 4) * 4;
    const int c0 = s0 + wx * 64 + (lane & 15);
#pragma unroll
    for (int i = 0; i < 4; ++i)
#pragma unroll
        for (int j = 0; j < 4; ++j)
#pragma unroll
            for (int r = 0; r < 4; ++r)
                ob[(size_t)(r0 + i * 16 + r) * SS + c0 + j * 16] = acc[i][j][r];
}

// ---------------------------------------------------------------------------
// Kernel 2 (fused): row-wise sparsemax + sparse PV. One wave per row.
// REVERSE block->row order: k_scores writes rows in ascending dispatch order,
// so at its end the 256 MB L3 holds the LAST-written ~95% of the 268 MB score
// tensor. Reading newest-first turns those into L3 hits instead of the
// worst-case LRU traversal of ascending order. Gate/V stores stay nontemporal
// so our own writes don't evict the resident scores.
// tau: 10 bisection brackets + 4 Michelot refines (exact fixpoint).
// ---------------------------------------------------------------------------
__global__ __launch_bounds__(256) void k_sparsemax_pv(float* __restrict__ G,
                                                      float* __restrict__ A,
                                                      const float* __restrict__ Val,
                                                      float* __restrict__ Vout) {
    const int t = threadIdx.x;
    const int lane = t & 63;
    const size_t rblk = (size_t)(gridDim.x - 1 - blockIdx.x);   // reversed
    const size_t row = rblk * 4 + (t >> 6);                     // over B*N
    const int b = (int)(row >> 11);                             // NN = 2048
    float* z = G + row * SS;
    float* arow = A + row * SS;
    const float* vb = Val + (size_t)b * SS * DD;

    float v[32];
#pragma unroll
    for (int c = 0; c < 8; ++c) {
        float4 zz = *(const float4*)(z + c * 256 + (lane << 2));
        v[c * 4 + 0] = zz.x; v[c * 4 + 1] = zz.y; v[c * 4 + 2] = zz.z; v[c * 4 + 3] = zz.w;
    }

    // wave max
    float m = v[0];
#pragma unroll
    for (int j = 1; j < 32; ++j) m = fmaxf(m, v[j]);
#pragma unroll
    for (int off = 32; off > 0; off >>= 1) m = fmaxf(m, __shfl_xor(m, off, 64));

    // bisection to bracket the support: g(lo) >= 1 >= g(hi)
    float lo = m - 1.0f, hi = m;
    for (int it = 0; it < 10; ++it) {
        float mid = 0.5f * (lo + hi);
        float p = 0.f;
#pragma unroll
        for (int j = 0; j < 32; ++j) p += fmaxf(v[j] - mid, 0.f);
#pragma unroll
        for (int off = 32; off > 0; off >>= 1) p += __shfl_xor(p, off, 64);
        if (p >= 1.0f) lo = mid; else hi = mid;
    }

    // Michelot refines: tau increases monotonically to the exact threshold
    float tau = lo;
#pragma unroll
    for (int it = 0; it < 4; ++it) {
        float cnt = 0.f, s = 0.f;
#pragma unroll
        for (int j = 0; j < 32; ++j) {
            if (v[j] > tau) { cnt += 1.0f; s += v[j]; }
        }
#pragma unroll
        for (int off = 32; off > 0; off >>= 1) {
            cnt += __shfl_xor(cnt, off, 64);
            s   += __shfl_xor(s, off, 64);
        }
        tau = (s - 1.0f) / cnt;
    }

    // gates (kept in registers for PV), dual nontemporal store
    float g[32];
#pragma unroll
    for (int c = 0; c < 8; ++c) {
#pragma unroll
        for (int q = 0; q < 4; ++q) g[c * 4 + q] = fmaxf(v[c * 4 + q] - tau, 0.f);
        nt_store4(z + c * 256 + (lane << 2),    g[c * 4], g[c * 4 + 1], g[c * 4 + 2], g[c * 4 + 3]);
        nt_store4(arow + c * 256 + (lane << 2), g[c * 4], g[c * 4 + 1], g[c * 4 + 2], g[c * 4 + 3]);
    }

    // sparse PV from registers
    float4 acc = make_float4(0.f, 0.f, 0.f, 0.f);
#pragma unroll
    for (int c = 0; c < 8; ++c) {
#pragma unroll
        for (int q = 0; q < 4; ++q) {
            float a = g[c * 4 + q];
            unsigned long long mask = __ballot(a != 0.0f);
            while (mask) {
                int src = __builtin_ctzll(mask);
                mask &= mask - 1;
                float aa = __shfl(a, src, 64);
                int s = c * 256 + src * 4 + q;
                float4 vv = *(const float4*)(vb + (size_t)s * DD + lane * 4);
                acc.x += aa * vv.x;
                acc.y += aa * vv.y;
                acc.z += aa * vv.z;
                acc.w += aa * vv.w;
            }
        }
    }

    nt_store4(Vout + row * DD + lane * 4, acc.x, acc.y, acc.z, acc.w);
}

extern "C" void kernel_launch(void* const* d_in, const int* in_sizes, int n_in,
                              void* d_out, int out_size, void* d_ws, size_t ws_size,
                              hipStream_t stream) {
    const float* Q = (const float*)d_in[0];
    const float* K = (const float*)d_in[1];
    const float* V = (const float*)d_in[2];

    float* out  = (float*)d_out;
    float* Vout = out;                                   // [B,N,D]
    float* Aout = out + (size_t)BB * NN * DD;            // [B,N,S]
    float* Gout = Aout + (size_t)BB * NN * SS;           // [B,N,S]

    // 0) split Q,K into bf16 hi/lo stash (lives in Aout region until sparsemax)
    __bf16* stash = (__bf16*)Aout;
    hipLaunchKernelGGL(k_convert, dim3((2 * EE / 4) / 256), dim3(256), 0, stream, Q, K, stash);

    // 1) scores -> gates region (3-term split-bf16 MFMA)
    dim3 g1(SS / 128, NN / 128, BB);
    hipLaunchKernelGGL(k_scores_mfma, g1, dim3(256), 0, stream, stash, Gout);

    // 2) fused sparsemax + PV: gates in-place, duplicate into A, V out
    hipLaunchKernelGGL(k_sparsemax_pv, dim3((BB * NN) / 4), dim3(256), 0, stream,
                       Gout, Aout, V, Vout);
}

// Round 7
// 735.185 us; speedup vs baseline: 1.0876x; 1.0375x over previous
//
#include <hip/hip_runtime.h>
#include <hip/hip_bf16.h>

// Problem constants (B=16, N=S=2048, D=256, fp32 in/out).
#define BB 16
#define NN 2048
#define SS 2048
#define DD 256
#define EE (BB * NN * DD)  // 8388608 elements per tensor

typedef _Float16 f16x8 __attribute__((ext_vector_type(8)));
typedef _Float16 f16x4 __attribute__((ext_vector_type(4)));
typedef float floatx4 __attribute__((ext_vector_type(4)));

__device__ __forceinline__ void async16(const _Float16* g, _Float16* l) {
    __builtin_amdgcn_global_load_lds((__attribute__((address_space(1))) void*)g,
                                     (__attribute__((address_space(3))) void*)l, 16, 0, 0);
}

__device__ __forceinline__ void nt_store4(float* p, float x, float y, float z, float w) {
    floatx4 v = {x, y, z, w};
    __builtin_nontemporal_store(v, (floatx4*)p);
}

// ---------------------------------------------------------------------------
// Kernel 0: fp16 split. Q -> (Qh, Ql) with q = qh + ql exact to ~2^-22;
// K -> Kh only. Asymmetric 2-term scores qh*kh + ql*kh then have error only
// from k's fp16 rounding: max ~0.026 over 67M scores (threshold 0.104).
// stash (fp16): Qh[EE] | Ql[EE] | Kh[EE] = 50 MB, in the A-output region
// (overwritten later by the fused sparsemax kernel).
// ---------------------------------------------------------------------------
__global__ __launch_bounds__(256) void k_convert(const float* __restrict__ Q,
                                                 const float* __restrict__ K,
                                                 _Float16* __restrict__ stash) {
    size_t idx = ((size_t)blockIdx.x * 256 + threadIdx.x) * 4;  // over 2*EE elems
    if (idx < (size_t)EE) {
        float4 v = *(const float4*)(Q + idx);
        f16x4 h, l;
        h.x = (_Float16)v.x; h.y = (_Float16)v.y; h.z = (_Float16)v.z; h.w = (_Float16)v.w;
        l.x = (_Float16)(v.x - (float)h.x);
        l.y = (_Float16)(v.y - (float)h.y);
        l.z = (_Float16)(v.z - (float)h.z);
        l.w = (_Float16)(v.w - (float)h.w);
        *(f16x4*)(stash + idx) = h;
        *(f16x4*)(stash + (size_t)EE + idx) = l;
    } else {
        size_t off = idx - (size_t)EE;
        float4 v = *(const float4*)(K + off);
        f16x4 h;
        h.x = (_Float16)v.x; h.y = (_Float16)v.y; h.z = (_Float16)v.z; h.w = (_Float16)v.w;
        *(f16x4*)(stash + 2 * (size_t)EE + off) = h;
    }
}

// ---------------------------------------------------------------------------
// Kernel 1: scores = Q @ K^T via 2-term fp16 MFMA (qh*kh + ql*kh).
// 128x128 tile / block, 4 waves each 64x64 (4x4 tiles of 16x16x32_f16).
// Structure identical to the measured R3/R6 kernel, minus one term/buffer.
// Normal cached C-writes (leave scores L3-resident for the next kernel).
// ---------------------------------------------------------------------------
__global__ __launch_bounds__(256) void k_scores_mfma(const _Float16* __restrict__ stash,
                                                     float* __restrict__ out) {
    __shared__ _Float16 Qh[128 * 32];
    __shared__ _Float16 Ql[128 * 32];
    __shared__ _Float16 Kh[128 * 32];

    const _Float16* Qhi = stash;
    const _Float16* Qlo = stash + (size_t)EE;
    const _Float16* Khi = stash + 2 * (size_t)EE;

    const int b  = blockIdx.z;
    const int n0 = blockIdx.y * 128;
    const int s0 = blockIdx.x * 128;

    const int t    = threadIdx.x;
    const int wave = t >> 6;
    const int lane = t & 63;

    // staging: row within 64-row pass, 16B d-chunk
    const int srow = (wave << 4) + (lane >> 2);   // 0..63
    const int sd   = (lane & 3) << 3;             // 0,8,16,24 elems
    const int lds0 = srow * 32 + sd;
    const size_t qg = (size_t)b * NN * DD + (size_t)(n0 + srow) * DD + sd;
    const size_t kg = (size_t)b * SS * DD + (size_t)(s0 + srow) * DD + sd;

    // fragment read offsets
    const int wy = wave >> 1, wx = wave & 1;
    const int frag = (lane & 15) * 32 + (lane >> 4) * 8;

    floatx4 acc[4][4] = {};

    for (int d0 = 0; d0 < DD; d0 += 32) {
        __syncthreads();
        async16(Qhi + qg + d0,            &Qh[lds0]);
        async16(Qhi + qg + d0 + 64 * DD,  &Qh[lds0 + 2048]);
        async16(Qlo + qg + d0,            &Ql[lds0]);
        async16(Qlo + qg + d0 + 64 * DD,  &Ql[lds0 + 2048]);
        async16(Khi + kg + d0,            &Kh[lds0]);
        async16(Khi + kg + d0 + 64 * DD,  &Kh[lds0 + 2048]);
        __syncthreads();

        f16x8 qh[4], ql[4], kh[4];
#pragma unroll
        for (int i = 0; i < 4; ++i) {
            qh[i] = *(const f16x8*)&Qh[(wy * 64 + i * 16) * 32 + frag];
            ql[i] = *(const f16x8*)&Ql[(wy * 64 + i * 16) * 32 + frag];
            kh[i] = *(const f16x8*)&Kh[(wx * 64 + i * 16) * 32 + frag];
        }
#pragma unroll
        for (int i = 0; i < 4; ++i)
#pragma unroll
            for (int j = 0; j < 4; ++j) {
                acc[i][j] = __builtin_amdgcn_mfma_f32_16x16x32_f16(qh[i], kh[j], acc[i][j], 0, 0, 0);
                acc[i][j] = __builtin_amdgcn_mfma_f32_16x16x32_f16(ql[i], kh[j], acc[i][j], 0, 0, 0);
            }
    }

    // C/D layout: col = lane&15, row = (lane>>4)*4 + reg
    float* ob = out + (size_t)b * NN * SS;
    const int r0 = n0 + wy * 64 + (lane >> 4) * 4;
    const int c0 = s0 + wx * 64 + (lane & 15);
#pragma unroll
    for (int i = 0; i < 4; ++i)
#pragma unroll
        for (int j = 0; j < 4; ++j)
#pragma unroll
            for (int r = 0; r < 4; ++r)
                ob[(size_t)(r0 + i * 16 + r) * SS + c0 + j * 16] = acc[i][j][r];
}

// ---------------------------------------------------------------------------
// Kernel 2 (fused): row-wise sparsemax + sparse PV (R6, measured). One wave
// per row, REVERSED block->row order to harvest L3-resident (newest) scores.
// tau: 10 bisection brackets + 4 Michelot refines (exact fixpoint). Gate/V
// stores nontemporal so our writes don't evict resident scores.
// ---------------------------------------------------------------------------
__global__ __launch_bounds__(256) void k_sparsemax_pv(float* __restrict__ G,
                                                      float* __restrict__ A,
                                                      const float* __restrict__ Val,
                                                      float* __restrict__ Vout) {
    const int t = threadIdx.x;
    const int lane = t & 63;
    const size_t rblk = (size_t)(gridDim.x - 1 - blockIdx.x);   // reversed
    const size_t row = rblk * 4 + (t >> 6);                     // over B*N
    const int b = (int)(row >> 11);                             // NN = 2048
    float* z = G + row * SS;
    float* arow = A + row * SS;
    const float* vb = Val + (size_t)b * SS * DD;

    float v[32];
#pragma unroll
    for (int c = 0; c < 8; ++c) {
        float4 zz = *(const float4*)(z + c * 256 + (lane << 2));
        v[c * 4 + 0] = zz.x; v[c * 4 + 1] = zz.y; v[c * 4 + 2] = zz.z; v[c * 4 + 3] = zz.w;
    }

    // wave max
    float m = v[0];
#pragma unroll
    for (int j = 1; j < 32; ++j) m = fmaxf(m, v[j]);
#pragma unroll
    for (int off = 32; off > 0; off >>= 1) m = fmaxf(m, __shfl_xor(m, off, 64));

    // bisection to bracket the support: g(lo) >= 1 >= g(hi)
    float lo = m - 1.0f, hi = m;
    for (int it = 0; it < 10; ++it) {
        float mid = 0.5f * (lo + hi);
        float p = 0.f;
#pragma unroll
        for (int j = 0; j < 32; ++j) p += fmaxf(v[j] - mid, 0.f);
#pragma unroll
        for (int off = 32; off > 0; off >>= 1) p += __shfl_xor(p, off, 64);
        if (p >= 1.0f) lo = mid; else hi = mid;
    }

    // Michelot refines: tau increases monotonically to the exact threshold
    float tau = lo;
#pragma unroll
    for (int it = 0; it < 4; ++it) {
        float cnt = 0.f, s = 0.f;
#pragma unroll
        for (int j = 0; j < 32; ++j) {
            if (v[j] > tau) { cnt += 1.0f; s += v[j]; }
        }
#pragma unroll
        for (int off = 32; off > 0; off >>= 1) {
            cnt += __shfl_xor(cnt, off, 64);
            s   += __shfl_xor(s, off, 64);
        }
        tau = (s - 1.0f) / cnt;
    }

    // gates (kept in registers for PV), dual nontemporal store
    float g[32];
#pragma unroll
    for (int c = 0; c < 8; ++c) {
#pragma unroll
        for (int q = 0; q < 4; ++q) g[c * 4 + q] = fmaxf(v[c * 4 + q] - tau, 0.f);
        nt_store4(z + c * 256 + (lane << 2),    g[c * 4], g[c * 4 + 1], g[c * 4 + 2], g[c * 4 + 3]);
        nt_store4(arow + c * 256 + (lane << 2), g[c * 4], g[c * 4 + 1], g[c * 4 + 2], g[c * 4 + 3]);
    }

    // sparse PV from registers
    float4 acc = make_float4(0.f, 0.f, 0.f, 0.f);
#pragma unroll
    for (int c = 0; c < 8; ++c) {
#pragma unroll
        for (int q = 0; q < 4; ++q) {
            float a = g[c * 4 + q];
            unsigned long long mask = __ballot(a != 0.0f);
            while (mask) {
                int src = __builtin_ctzll(mask);
                mask &= mask - 1;
                float aa = __shfl(a, src, 64);
                int s = c * 256 + src * 4 + q;
                float4 vv = *(const float4*)(vb + (size_t)s * DD + lane * 4);
                acc.x += aa * vv.x;
                acc.y += aa * vv.y;
                acc.z += aa * vv.z;
                acc.w += aa * vv.w;
            }
        }
    }

    nt_store4(Vout + row * DD + lane * 4, acc.x, acc.y, acc.z, acc.w);
}

extern "C" void kernel_launch(void* const* d_in, const int* in_sizes, int n_in,
                              void* d_out, int out_size, void* d_ws, size_t ws_size,
                              hipStream_t stream) {
    const float* Q = (const float*)d_in[0];
    const float* K = (const float*)d_in[1];
    const float* V = (const float*)d_in[2];

    float* out  = (float*)d_out;
    float* Vout = out;                                   // [B,N,D]
    float* Aout = out + (size_t)BB * NN * DD;            // [B,N,S]
    float* Gout = Aout + (size_t)BB * NN * SS;           // [B,N,S]

    // 0) fp16 split: Qh|Ql|Kh stash (lives in Aout region until sparsemax)
    _Float16* stash = (_Float16*)Aout;
    hipLaunchKernelGGL(k_convert, dim3((2 * EE / 4) / 256), dim3(256), 0, stream, Q, K, stash);

    // 1) scores -> gates region (2-term fp16 MFMA)
    dim3 g1(SS / 128, NN / 128, BB);
    hipLaunchKernelGGL(k_scores_mfma, g1, dim3(256), 0, stream, stash, Gout);

    // 2) fused sparsemax + PV: gates in-place, duplicate into A, V out
    hipLaunchKernelGGL(k_sparsemax_pv, dim3((BB * NN) / 4), dim3(256), 0, stream,
                       Gout, Aout, V, Vout);
}